// Round 7
// baseline (1740.650 us; speedup 1.0000x reference)
//
#include <hip/hip_runtime.h>
#include <hip/hip_bf16.h>

// B=4096, L=100 (SEQLEN=99), d=256, K=2d=512.
// x[b,t,:] = [qa[b,t,:], q[b,t,:]]  (t=0..98)
// gate=sigmoid(x@Wg^T+bg), kq=tanh(x@Wk^T+bk), reset=sigmoid(x@Wr^T+br)
// h_0 = exp; h_{t+1} = r_t*h_t + (1-r_t)*(gate_t*kq_t); out[b] = [exp, h_1..h_99]
//
// Round-7: two blocks per b (grid 8192), 512 threads (8 waves), wave w owns
// one 16-col n-tile: d in [dhalf*128 + w*16, +16) -> 84 acc f32/thread.
//  - x staged as BF16 k-quarters (99 x 128 bf16 = 25344 B), double-buffered
//    (50688 B LDS), register-path commit-immediate (load f32x4 -> cvt_pk ->
//    ds_write_b64; transient regs only). Conversion happens ONCE per element
//    (round 6 redid it per fragment read: 57% VALUBusy).
//  - fragment read = ONE ds_read_b128; addr = pre[mt] ^ (kk*64) (swizzle math
//    hoisted; XOR swizzle byte = (c*8) ^ ((row&7)<<4) on a 256 B row).
//  - LDS 50.7 KB + __launch_bounds__(512,4) (VGPR<=128; R6 landed at 124 with
//    a fatter loop) -> 2 blocks/CU co-resident: partner block's MFMA hides
//    this block's staging stalls. Pairing (g, g+8) keeps both halves of one b
//    on the same XCD for L2 reuse of x.
//  - recurrence fully in-register (affine-map compose + shuffle scan).

typedef __attribute__((ext_vector_type(4))) float f32x4;
typedef __attribute__((ext_vector_type(8))) short short8;

union BF8 { short8 s; unsigned short u[8]; unsigned int w4[4]; };

static constexpr int QT_BYTES = 99 * 256;        // one bf16 k-quarter, 25344 B

__device__ __forceinline__ unsigned short f2bf(float f) {
  unsigned int u = __float_as_uint(f);
  return (unsigned short)((u + 0x7fffu + ((u >> 16) & 1u)) >> 16);   // RNE
}

__device__ __forceinline__ unsigned int pk2bf(float lo, float hi) {
  __hip_bfloat162 h = __float22bfloat162_rn(make_float2(lo, hi));    // v_cvt_pk_bf16_f32
  union { __hip_bfloat162 h2; unsigned int u; } cv;
  cv.h2 = h;
  return cv.u;
}

__device__ __forceinline__ float sigm(float x) { return 1.f / (1.f + __expf(-x)); }
__device__ __forceinline__ float tanh_(float x) {
  x = fminf(fmaxf(x, -15.f), 15.f);
  float e = __expf(2.f * x);
  return (e - 1.f) / (e + 1.f);
}

// Pack Wg|Wk|Wr (each 256x512 f32, row-major) into bf16 B-fragment order:
// [nt(48)][ks(16)][lane(64)][j(8)]; value = W_sel[nt%16*16 + (l&15)][ks*32+(l>>4)*8+j]
__global__ void pack_w(const float* __restrict__ Wg, const float* __restrict__ Wk,
                       const float* __restrict__ Wr, unsigned short* __restrict__ out) {
  int idx = blockIdx.x * 256 + threadIdx.x;        // 0 .. 49151  (48*16*64)
  int l = idx & 63;
  int rest = idx >> 6;
  int ks = rest & 15;
  int nt = rest >> 4;                              // 0..47
  int sel = nt >> 4;
  const float* W = (sel == 0) ? Wg : ((sel == 1) ? Wk : Wr);
  int n = ((nt & 15) * 16) + (l & 15);             // 0..255
  const float* p = W + (size_t)n * 512 + ks * 32 + ((l >> 4) * 8);
  unsigned short* o = out + (size_t)idx * 8;
#pragma unroll
  for (int j = 0; j < 8; ++j) o[j] = f2bf(p[j]);
}

template <bool PACKED>
__device__ __forceinline__ short8 ldB(const unsigned short* __restrict__ wpk,
                                      const float* __restrict__ W,
                                      int nt_global, int ks, int l) {
  if constexpr (PACKED) {
    return *(const short8*)(wpk + (((size_t)nt_global * 16 + ks) * 64 + l) * 8);
  } else {
    int n = ((nt_global & 15) * 16) + (l & 15);
    const float* p = W + (size_t)n * 512 + ks * 32 + ((l >> 4) * 8);
    f32x4 v0 = *(const f32x4*)p;
    f32x4 v1 = *(const f32x4*)(p + 4);
    BF8 r;
#pragma unroll
    for (int j = 0; j < 4; ++j) { r.u[j] = f2bf(v0[j]); r.u[4 + j] = f2bf(v1[j]); }
    return r.s;
  }
}

template <bool PACKED>
__global__ __launch_bounds__(512, 4) void fused_kernel(
    const float* __restrict__ q, const float* __restrict__ qa,
    const float* __restrict__ expw,
    const float* __restrict__ Wg, const float* __restrict__ bg,
    const float* __restrict__ Wk, const float* __restrict__ bk,
    const float* __restrict__ Wr, const float* __restrict__ br,
    const unsigned short* __restrict__ wpk,
    float* __restrict__ out) {
  __shared__ char smem[2 * QT_BYTES];              // 50688 B -> 2 blocks/CU
  const int g = blockIdx.x;
  const int dhalf = (g >> 3) & 1;                  // pairs (g, g+8): same b, same XCD
  const int b = (g & 7) | ((g >> 4) << 3);         // bijective over 8192
  const int tid = threadIdx.x;
  const int w = tid >> 6;                          // wave 0..7
  const int l = tid & 63;
  const int lrow = l & 15;
  const int lgrp = l >> 4;
  const int ntb = dhalf * 8 + w;                   // this wave's n-tile (0..15)

  const float* xqa = qa + (size_t)b * 25600;       // x[:, 0:256)
  const float* xq  = q  + (size_t)b * 25600;       // x[:, 256:512)

  // Stage quarter qq (k in [qq*128,+128)) as bf16 into buffer bufi.
  // 3168 f32x4 chunks (99 rows x 32); coalesced loads; transient regs only.
  // LDS byte-in-row = (c*8) ^ ((row&7)<<4)  (8B write granularity).
#define STAGE(qq, bufi)                                                      \
  {                                                                          \
    const float* srcb = ((qq) < 2 ? xqa : xq) + ((qq) & 1) * 128;            \
    char* dst = smem + (bufi) * QT_BYTES;                                    \
    _Pragma("unroll")                                                        \
    for (int it = 0; it < 7; ++it) {                                         \
      int cid = it * 512 + tid;                                              \
      if (cid < 3168) {                                                      \
        int row = cid >> 5, c = cid & 31;                                    \
        f32x4 v = *(const f32x4*)(srcb + row * 256 + c * 4);                 \
        unsigned long long pkd =                                             \
            ((unsigned long long)pk2bf(v[2], v[3]) << 32) | pk2bf(v[0], v[1]); \
        int byte = row * 256 + ((c * 8) ^ ((row & 7) << 4));                 \
        *(unsigned long long*)(dst + byte) = pkd;                            \
      }                                                                      \
    }                                                                        \
  }

  STAGE(0, 0);
  __syncthreads();

  f32x4 accG[7], accK[7], accR[7];                 // 84 f32/thread
#pragma unroll
  for (int mt = 0; mt < 7; ++mt) {
    accG[mt] = (f32x4){0.f, 0.f, 0.f, 0.f};
    accK[mt] = (f32x4){0.f, 0.f, 0.f, 0.f};
    accR[mt] = (f32x4){0.f, 0.f, 0.f, 0.f};
  }

  // hoisted fragment addresses: addr = pre[mt] ^ (kk*64)
  int pre[7];
#pragma unroll
  for (int mt = 0; mt < 7; ++mt) {
    int t = mt * 16 + lrow;
    t = (t > 98) ? 98 : t;                         // clamped lanes broadcast row 98
    pre[mt] = t * 256 + ((lgrp * 16) ^ ((t & 7) << 4));
  }

#pragma unroll
  for (int qq = 0; qq < 4; ++qq) {
    if (qq < 3) STAGE(qq + 1, (qq + 1) & 1);       // other buffer; overlaps GEMM
    const char* base = smem + (qq & 1) * QT_BYTES;
#pragma unroll
    for (int kk = 0; kk < 4; ++kk) {
      const int ks = qq * 4 + kk;
      short8 bG = ldB<PACKED>(wpk, Wg, ntb, ks, l);
      short8 bK = ldB<PACKED>(wpk, Wk, 16 + ntb, ks, l);
      short8 bR = ldB<PACKED>(wpk, Wr, 32 + ntb, ks, l);
#pragma unroll
      for (int mt = 0; mt < 7; ++mt) {
        BF8 a;
        a.s = *(const short8*)(base + (pre[mt] ^ (kk * 64)));   // 1 ds_read_b128
        accG[mt] = __builtin_amdgcn_mfma_f32_16x16x32_bf16(a.s, bG, accG[mt], 0, 0, 0);
        accK[mt] = __builtin_amdgcn_mfma_f32_16x16x32_bf16(a.s, bK, accK[mt], 0, 0, 0);
        accR[mt] = __builtin_amdgcn_mfma_f32_16x16x32_bf16(a.s, bR, accR[mt], 0, 0, 0);
      }
    }
    if (qq < 3) __syncthreads();                   // staged visible; reads of next buf done
  }

  // ---- epilogue: activations + in-register affine scan + direct stores ----
  // acc layout per mt: lane (lrow,lgrp) holds t = mt*16 + lgrp*4 + r,
  // d = ntb*16 + lrow. Step map: h' = rr*h + cc, cc = (1-rr)*gate*kq.
  float* ob = out + (size_t)b * 25600;
  {
    const int d = ntb * 16 + lrow;
    const float bgv = bg[d], bkv = bk[d], brv = br[d];
    float h = expw[d];
    if (lgrp == 0) ob[d] = h;                      // out[b,0,:] = exp
#pragma unroll
    for (int mt = 0; mt < 7; ++mt) {
      float rr[4], cc[4];
#pragma unroll
      for (int r = 0; r < 4; ++r) {
        const int t = mt * 16 + lgrp * 4 + r;
        if (t < 99) {
          float rv = sigm(accR[mt][r] + brv);
          float gv = sigm(accG[mt][r] + bgv);
          float kv = tanh_(accK[mt][r] + bkv);
          rr[r] = rv;
          cc[r] = (1.f - rv) * (gv * kv);
        } else { rr[r] = 1.f; cc[r] = 0.f; }       // identity step for padding
      }
      // compose this lane's 4 steps: h -> A*h + B
      const float A  = ((rr[0] * rr[1]) * rr[2]) * rr[3];
      const float Bc = ((cc[0] * rr[1] + cc[1]) * rr[2] + cc[2]) * rr[3] + cc[3];
      // shuffle scan across the 4 lgrp groups (same lrow column)
      float hcur = h, hstart = h;
#pragma unroll
      for (int gg = 0; gg < 4; ++gg) {
        float ag  = __shfl(A,  lrow + (gg << 4), 64);
        float bg_ = __shfl(Bc, lrow + (gg << 4), 64);
        hstart = (lgrp == gg) ? hcur : hstart;     // exclusive prefix for own group
        hcur = __builtin_fmaf(ag, hcur, bg_);
      }
      h = hcur;                                    // carry to next m-tile
      // reconstruct the 4 per-step h values and store
      float hh = hstart;
#pragma unroll
      for (int r = 0; r < 4; ++r) {
        const int t = mt * 16 + lgrp * 4 + r;
        hh = __builtin_fmaf(rr[r], hh, cc[r]);
        if (t < 99) ob[(t + 1) * 256 + d] = hh;
      }
    }
  }
#undef STAGE
}

extern "C" void kernel_launch(void* const* d_in, const int* in_sizes, int n_in,
                              void* d_out, int out_size, void* d_ws, size_t ws_size,
                              hipStream_t stream) {
  const float* q    = (const float*)d_in[0];
  const float* qa   = (const float*)d_in[1];
  const float* expw = (const float*)d_in[2];
  const float* Wg   = (const float*)d_in[3];
  const float* bg   = (const float*)d_in[4];
  const float* Wk   = (const float*)d_in[5];
  const float* bk   = (const float*)d_in[6];
  const float* Wr   = (const float*)d_in[7];
  const float* br   = (const float*)d_in[8];
  float* out = (float*)d_out;

  const bool packed = ws_size >= (size_t)(48 * 16 * 64 * 8 * 2);

  if (packed) {
    unsigned short* wpk = (unsigned short*)d_ws;
    pack_w<<<192, 256, 0, stream>>>(Wg, Wk, Wr, wpk);
    fused_kernel<true><<<8192, 512, 0, stream>>>(q, qa, expw, Wg, bg, Wk, bk, Wr, br, wpk, out);
  } else {
    fused_kernel<false><<<8192, 512, 0, stream>>>(q, qa, expw, Wg, bg, Wk, bk, Wr, br, nullptr, out);
  }
}

// Round 8
// 1334.347 us; speedup vs baseline: 1.3045x; 1.3045x over previous
//
#include <hip/hip_runtime.h>
#include <hip/hip_bf16.h>

// B=4096, L=100 (SEQLEN=99), d=256, K=2d=512.
// x[b,t,:] = [qa[b,t,:], q[b,t,:]]  (t=0..98)
// gate=sigmoid(x@Wg^T+bg), kq=tanh(x@Wk^T+bk), reset=sigmoid(x@Wr^T+br)
// h_0 = exp; h_{t+1} = r_t*h_t + (1-r_t)*(gate_t*kq_t); out[b] = [exp, h_1..h_99]
//
// Round-8: pre-pack BOTH operands to bf16 fragment order in d_ws, then a
// staging-free main kernel.
//  - pack_x: x -> bf16 A-fragments [b][mt 7][ks 16][lane 64]x16B (470 MB ws).
//    One-shot BW pass; all f32->bf16 conversion leaves the main kernel.
//  - main: grid 16384 = 4 blocks per b (dquad = 64 d-cols each); 8 waves =
//    2 mhalf (mt 0-3 / 4-6) x 4 n-tiles. Accs = 48 f32/thread (R7's 84 broke
//    the 128-reg budget for 4 waves/SIMD -> AGPR spill). A and W fragments
//    are coalesced 16B/lane GLOBAL loads (L2-resident; 4 same-b blocks pinned
//    to one XCD by the g&7 decode). NO LDS staging, NO barriers in the GEMM
//    loop. __launch_bounds__(512,4) -> 2 blocks/CU.
//  - recurrence: in-register affine scan; one 64-float LDS handoff of h(t=64)
//    from mhalf0 to mhalf1 (single barrier).
//  - fallback (ws too small): PACKED=false gathers f32 + converts inline.

typedef __attribute__((ext_vector_type(4))) float f32x4;
typedef __attribute__((ext_vector_type(8))) short short8;

union BF8 { short8 s; unsigned short u[8]; unsigned int w4[4]; };

static constexpr size_t W_BYTES  = (size_t)48 * 16 * 64 * 16;          // 786432
static constexpr size_t X_CHUNKS = (size_t)4096 * 7 * 16 * 64;         // 29.36M
static constexpr size_t X_BYTES  = X_CHUNKS * 16;                      // 469.76 MB
static constexpr size_t WS_NEED  = W_BYTES + X_BYTES;

__device__ __forceinline__ unsigned short f2bf(float f) {
  unsigned int u = __float_as_uint(f);
  return (unsigned short)((u + 0x7fffu + ((u >> 16) & 1u)) >> 16);   // RNE
}

__device__ __forceinline__ unsigned int pk2bf(float lo, float hi) {
  __hip_bfloat162 h = __float22bfloat162_rn(make_float2(lo, hi));    // v_cvt_pk_bf16_f32
  union { __hip_bfloat162 h2; unsigned int u; } cv;
  cv.h2 = h;
  return cv.u;
}

__device__ __forceinline__ float sigm(float x) { return 1.f / (1.f + __expf(-x)); }
__device__ __forceinline__ float tanh_(float x) {
  x = fminf(fmaxf(x, -15.f), 15.f);
  float e = __expf(2.f * x);
  return (e - 1.f) / (e + 1.f);
}

// Pack Wg|Wk|Wr (each 256x512 f32, row-major) into bf16 B-fragment order:
// [nt(48)][ks(16)][lane(64)][j(8)]; value = W_sel[nt%16*16 + (l&15)][ks*32+(l>>4)*8+j]
__global__ void pack_w(const float* __restrict__ Wg, const float* __restrict__ Wk,
                       const float* __restrict__ Wr, unsigned short* __restrict__ out) {
  int idx = blockIdx.x * 256 + threadIdx.x;        // 0 .. 49151  (48*16*64)
  int l = idx & 63;
  int rest = idx >> 6;
  int ks = rest & 15;
  int nt = rest >> 4;                              // 0..47
  int sel = nt >> 4;
  const float* W = (sel == 0) ? Wg : ((sel == 1) ? Wk : Wr);
  int n = ((nt & 15) * 16) + (l & 15);             // 0..255
  const float* p = W + (size_t)n * 512 + ks * 32 + ((l >> 4) * 8);
  unsigned short* o = out + (size_t)idx * 8;
#pragma unroll
  for (int j = 0; j < 8; ++j) o[j] = f2bf(p[j]);
}

// Pack x into bf16 A-fragment order: chunk idx = ((b*7+mt)*16+ks)*64+l,
// value[j] = x[b][t = mt*16+(l&15), clamped 98][k = ks*32+(l>>4)*8+j]
__global__ void pack_x(const float* __restrict__ q, const float* __restrict__ qa,
                       unsigned short* __restrict__ xpk) {
  int idx = blockIdx.x * 256 + threadIdx.x;
  int l  = idx & 63;
  int r1 = idx >> 6;
  int ks = r1 & 15;
  int r2 = r1 >> 4;                                // b*7 + mt
  int mt = r2 % 7;
  int b  = r2 / 7;
  int t = mt * 16 + (l & 15);
  t = (t > 98) ? 98 : t;                           // pad rows replicate row 98
  int k = ks * 32 + ((l >> 4) << 3);
  const float* src = (k < 256) ? (qa + (size_t)b * 25600 + t * 256 + k)
                               : (q  + (size_t)b * 25600 + t * 256 + (k - 256));
  f32x4 v0 = *(const f32x4*)src;
  f32x4 v1 = *(const f32x4*)(src + 4);
  BF8 o;
  o.w4[0] = pk2bf(v0[0], v0[1]);
  o.w4[1] = pk2bf(v0[2], v0[3]);
  o.w4[2] = pk2bf(v1[0], v1[1]);
  o.w4[3] = pk2bf(v1[2], v1[3]);
  *(short8*)(xpk + (size_t)idx * 8) = o.s;
}

template <bool PACKED>
__device__ __forceinline__ short8 ldB(const unsigned short* __restrict__ wpk,
                                      const float* __restrict__ W,
                                      int nt_global, int ks, int l) {
  if constexpr (PACKED) {
    return *(const short8*)(wpk + (((size_t)nt_global * 16 + ks) * 64 + l) * 8);
  } else {
    int n = ((nt_global & 15) * 16) + (l & 15);
    const float* p = W + (size_t)n * 512 + ks * 32 + ((l >> 4) * 8);
    f32x4 v0 = *(const f32x4*)p;
    f32x4 v1 = *(const f32x4*)(p + 4);
    BF8 r;
    r.w4[0] = pk2bf(v0[0], v0[1]); r.w4[1] = pk2bf(v0[2], v0[3]);
    r.w4[2] = pk2bf(v1[0], v1[1]); r.w4[3] = pk2bf(v1[2], v1[3]);
    return r.s;
  }
}

template <bool PACKED>
__device__ __forceinline__ short8 ldA(const unsigned short* __restrict__ xpk,
                                      const float* __restrict__ qa,
                                      const float* __restrict__ q,
                                      int b, int mt, int ks, int l) {
  if constexpr (PACKED) {
    return *(const short8*)(xpk + ((((size_t)b * 7 + mt) * 16 + ks) * 64 + l) * 8);
  } else {
    int t = mt * 16 + (l & 15);
    t = (t > 98) ? 98 : t;
    int k = ks * 32 + ((l >> 4) << 3);
    const float* src = (k < 256) ? (qa + (size_t)b * 25600 + t * 256 + k)
                                 : (q  + (size_t)b * 25600 + t * 256 + (k - 256));
    f32x4 v0 = *(const f32x4*)src;
    f32x4 v1 = *(const f32x4*)(src + 4);
    BF8 r;
    r.w4[0] = pk2bf(v0[0], v0[1]); r.w4[1] = pk2bf(v0[2], v0[3]);
    r.w4[2] = pk2bf(v1[0], v1[1]); r.w4[3] = pk2bf(v1[2], v1[3]);
    return r.s;
  }
}

template <bool PACKED>
__global__ __launch_bounds__(512, 4) void fused_kernel(
    const float* __restrict__ q, const float* __restrict__ qa,
    const float* __restrict__ expw,
    const float* __restrict__ bg, const float* __restrict__ bk,
    const float* __restrict__ br,
    const float* __restrict__ Wg, const float* __restrict__ Wk,
    const float* __restrict__ Wr,
    const unsigned short* __restrict__ wpk,
    const unsigned short* __restrict__ xpk,
    float* __restrict__ out) {
  __shared__ float hlink[64];                      // h at t=64, per local d-col
  const int g = blockIdx.x;
  const int dquad = (g >> 3) & 3;                  // 4 same-b blocks 8 apart: same XCD
  const int b = (g & 7) | ((g >> 5) << 3);         // bijective over 16384
  const int tid = threadIdx.x;
  const int w = tid >> 6;                          // wave 0..7
  const int l = tid & 63;
  const int lrow = l & 15;
  const int lgrp = l >> 4;
  const int mhalf = w >> 2;                        // 0: mt 0-3, 1: mt 4-6
  const int nt = w & 3;
  const int ntg = dquad * 4 + nt;                  // global n-tile 0..15
  const int mt0 = mhalf * 4;
  const int Mloc = 4 - mhalf;                      // 4 or 3 m-tiles

  f32x4 accG[4], accK[4], accR[4];                 // 48 f32/thread (mhalf1 uses 3)
#pragma unroll
  for (int i = 0; i < 4; ++i) {
    accG[i] = (f32x4){0.f, 0.f, 0.f, 0.f};
    accK[i] = (f32x4){0.f, 0.f, 0.f, 0.f};
    accR[i] = (f32x4){0.f, 0.f, 0.f, 0.f};
  }

  // -------- GEMM: pure global-load + MFMA streaming, no LDS, no barriers ----
#pragma unroll 4
  for (int ks = 0; ks < 16; ++ks) {
    short8 bG = ldB<PACKED>(wpk, Wg, ntg, ks, l);
    short8 bK = ldB<PACKED>(wpk, Wk, 16 + ntg, ks, l);
    short8 bR = ldB<PACKED>(wpk, Wr, 32 + ntg, ks, l);
#pragma unroll
    for (int i = 0; i < 4; ++i) {
      if (i < Mloc) {                              // wave-uniform predicate
        short8 a = ldA<PACKED>(xpk, qa, q, b, mt0 + i, ks, l);
        accG[i] = __builtin_amdgcn_mfma_f32_16x16x32_bf16(a, bG, accG[i], 0, 0, 0);
        accK[i] = __builtin_amdgcn_mfma_f32_16x16x32_bf16(a, bK, accK[i], 0, 0, 0);
        accR[i] = __builtin_amdgcn_mfma_f32_16x16x32_bf16(a, bR, accR[i], 0, 0, 0);
      }
    }
  }

  // -------- epilogue: activations + in-register affine scan ----------------
  // acc[i] holds t = (mt0+i)*16 + lgrp*4 + r, d = ntg*16 + lrow.
  // Step: h' = rr*h + cc, cc = (1-rr)*gate*kq. Lane composes its 4 steps into
  // (A,Bc); 4-group shuffle scan; sequential carry across local m-tiles.
  const int d = ntg * 16 + lrow;
  const float bgv = bg[d], bkv = bk[d], brv = br[d];
  float* ob = out + (size_t)b * 25600;
  float h = 0.f;

#define SCAN_MT(I, MTG)                                                      \
  {                                                                          \
    float rr[4], cc[4];                                                      \
    _Pragma("unroll")                                                        \
    for (int r = 0; r < 4; ++r) {                                            \
      const int t = (MTG) * 16 + lgrp * 4 + r;                               \
      if (t < 99) {                                                          \
        float rv = sigm(accR[I][r] + brv);                                   \
        float gv = sigm(accG[I][r] + bgv);                                   \
        float kv = tanh_(accK[I][r] + bkv);                                  \
        rr[r] = rv;                                                          \
        cc[r] = (1.f - rv) * (gv * kv);                                      \
      } else { rr[r] = 1.f; cc[r] = 0.f; }                                   \
    }                                                                        \
    const float A  = ((rr[0] * rr[1]) * rr[2]) * rr[3];                      \
    const float Bc = ((cc[0] * rr[1] + cc[1]) * rr[2] + cc[2]) * rr[3] + cc[3]; \
    float hcur = h, hstart = h;                                              \
    _Pragma("unroll")                                                        \
    for (int gg = 0; gg < 4; ++gg) {                                         \
      float ag  = __shfl(A,  lrow + (gg << 4), 64);                          \
      float bg_ = __shfl(Bc, lrow + (gg << 4), 64);                          \
      hstart = (lgrp == gg) ? hcur : hstart;                                 \
      hcur = __builtin_fmaf(ag, hcur, bg_);                                  \
    }                                                                        \
    h = hcur;                                                                \
    float hh = hstart;                                                       \
    _Pragma("unroll")                                                        \
    for (int r = 0; r < 4; ++r) {                                            \
      const int t = (MTG) * 16 + lgrp * 4 + r;                               \
      hh = __builtin_fmaf(rr[r], hh, cc[r]);                                 \
      if (t < 99) ob[(t + 1) * 256 + d] = hh;                                \
    }                                                                        \
  }

  if (mhalf == 0) {
    h = expw[d];
    if (lgrp == 0) ob[d] = h;                      // out[b,0,:] = exp
    SCAN_MT(0, 0) SCAN_MT(1, 1) SCAN_MT(2, 2) SCAN_MT(3, 3)
    if (lgrp == 0) hlink[nt * 16 + lrow] = h;      // h at t=64
  }
  __syncthreads();
  if (mhalf == 1) {
    h = hlink[nt * 16 + lrow];
    SCAN_MT(0, 4) SCAN_MT(1, 5) SCAN_MT(2, 6)
  }
#undef SCAN_MT
}

extern "C" void kernel_launch(void* const* d_in, const int* in_sizes, int n_in,
                              void* d_out, int out_size, void* d_ws, size_t ws_size,
                              hipStream_t stream) {
  const float* q    = (const float*)d_in[0];
  const float* qa   = (const float*)d_in[1];
  const float* expw = (const float*)d_in[2];
  const float* Wg   = (const float*)d_in[3];
  const float* bg   = (const float*)d_in[4];
  const float* Wk   = (const float*)d_in[5];
  const float* bk   = (const float*)d_in[6];
  const float* Wr   = (const float*)d_in[7];
  const float* br   = (const float*)d_in[8];
  float* out = (float*)d_out;

  if (ws_size >= WS_NEED) {
    unsigned short* wpk = (unsigned short*)d_ws;
    unsigned short* xpk = (unsigned short*)((char*)d_ws + W_BYTES);
    pack_w<<<192, 256, 0, stream>>>(Wg, Wk, Wr, wpk);
    pack_x<<<(int)(X_CHUNKS / 256), 256, 0, stream>>>(q, qa, xpk);
    fused_kernel<true><<<16384, 512, 0, stream>>>(
        q, qa, expw, bg, bk, br, Wg, Wk, Wr, wpk, xpk, out);
  } else if (ws_size >= W_BYTES) {
    unsigned short* wpk = (unsigned short*)d_ws;
    pack_w<<<192, 256, 0, stream>>>(Wg, Wk, Wr, wpk);
    fused_kernel<false><<<16384, 512, 0, stream>>>(
        q, qa, expw, bg, bk, br, Wg, Wk, Wr, wpk, nullptr, out);
  } else {
    fused_kernel<false><<<16384, 512, 0, stream>>>(
        q, qa, expw, bg, bk, br, Wg, Wk, Wr, nullptr, nullptr, out);
  }
}

// Round 9
// 1289.776 us; speedup vs baseline: 1.3496x; 1.0346x over previous
//
#include <hip/hip_runtime.h>
#include <hip/hip_bf16.h>

// B=4096, L=100 (SEQLEN=99), d=256, K=2d=512.
// x[b,t,:] = [qa[b,t,:], q[b,t,:]]  (t=0..98)
// gate=sigmoid(x@Wg^T+bg), kq=tanh(x@Wk^T+bk), reset=sigmoid(x@Wr^T+br)
// h_0 = exp; h_{t+1} = r_t*h_t + (1-r_t)*(gate_t*kq_t); out[b] = [exp, h_1..h_99]
//
// Round-9 synthesis (constraint ledger from R3-R8):
//   * spill iff register-held staging OR >~50 accs under (512,4)  -> 48 accs,
//     commit-immediate staging (transient regs only)
//   * latency-bound iff no LDS tier for A          -> bf16 k-quarter staging
//   * barrier-serialized iff 1 block/CU            -> 50.7 KB LDS + (512,4)
//                                                      = 2 blocks/CU
// Structure: grid 16384 = 4 blocks per b (dquad owns 64 d-cols); 512 threads,
// 8 waves = 2 mhalf (mt 0-3 / 4-6) x 4 n-tiles -> 48 acc f32/thread.
//  - x staged in-kernel as bf16 k-quarters (99x128 bf16 = 25344 B), double
//    buffered, ONE barrier per quarter (R4-proven). No pack_x pass (saves
//    ~190 us + a 470 MB HBM round trip vs R8).
//  - LDS XOR swizzle widened to (t&15)<<4: fragment reads spread over all 16
//    16B-columns -> 4-way bank conflicts (was 8-way with (t&7)<<4).
//  - B fragments: 3 coalesced 16B/lane global loads per ks from pre-packed
//    wpk (L2-resident, shared by all blocks on the XCD).
//  - recurrence: in-register affine scan (compose 4 steps -> shuffle scan),
//    one 64-float LDS handoff of h(t=64) mhalf0 -> mhalf1.

typedef __attribute__((ext_vector_type(4))) float f32x4;
typedef __attribute__((ext_vector_type(8))) short short8;

union BF8 { short8 s; unsigned short u[8]; unsigned int w4[4]; };

static constexpr int QT_BYTES = 99 * 256;        // one bf16 k-quarter, 25344 B
static constexpr size_t W_BYTES = (size_t)48 * 16 * 64 * 16;   // 786432

__device__ __forceinline__ unsigned short f2bf(float f) {
  unsigned int u = __float_as_uint(f);
  return (unsigned short)((u + 0x7fffu + ((u >> 16) & 1u)) >> 16);   // RNE
}

__device__ __forceinline__ unsigned int pk2bf(float lo, float hi) {
  __hip_bfloat162 h = __float22bfloat162_rn(make_float2(lo, hi));    // v_cvt_pk_bf16_f32
  union { __hip_bfloat162 h2; unsigned int u; } cv;
  cv.h2 = h;
  return cv.u;
}

__device__ __forceinline__ float sigm(float x) { return 1.f / (1.f + __expf(-x)); }
__device__ __forceinline__ float tanh_(float x) {
  x = fminf(fmaxf(x, -15.f), 15.f);
  float e = __expf(2.f * x);
  return (e - 1.f) / (e + 1.f);
}

// Pack Wg|Wk|Wr (each 256x512 f32, row-major) into bf16 B-fragment order:
// [nt(48)][ks(16)][lane(64)][j(8)]; value = W_sel[nt%16*16 + (l&15)][ks*32+(l>>4)*8+j]
__global__ void pack_w(const float* __restrict__ Wg, const float* __restrict__ Wk,
                       const float* __restrict__ Wr, unsigned short* __restrict__ out) {
  int idx = blockIdx.x * 256 + threadIdx.x;        // 0 .. 49151  (48*16*64)
  int l = idx & 63;
  int rest = idx >> 6;
  int ks = rest & 15;
  int nt = rest >> 4;                              // 0..47
  int sel = nt >> 4;
  const float* W = (sel == 0) ? Wg : ((sel == 1) ? Wk : Wr);
  int n = ((nt & 15) * 16) + (l & 15);             // 0..255
  const float* p = W + (size_t)n * 512 + ks * 32 + ((l >> 4) * 8);
  unsigned short* o = out + (size_t)idx * 8;
#pragma unroll
  for (int j = 0; j < 8; ++j) o[j] = f2bf(p[j]);
}

template <bool PACKED>
__device__ __forceinline__ short8 ldB(const unsigned short* __restrict__ wpk,
                                      const float* __restrict__ W,
                                      int nt_global, int ks, int l) {
  if constexpr (PACKED) {
    return *(const short8*)(wpk + (((size_t)nt_global * 16 + ks) * 64 + l) * 8);
  } else {
    int n = ((nt_global & 15) * 16) + (l & 15);
    const float* p = W + (size_t)n * 512 + ks * 32 + ((l >> 4) * 8);
    f32x4 v0 = *(const f32x4*)p;
    f32x4 v1 = *(const f32x4*)(p + 4);
    BF8 r;
    r.w4[0] = pk2bf(v0[0], v0[1]); r.w4[1] = pk2bf(v0[2], v0[3]);
    r.w4[2] = pk2bf(v1[0], v1[1]); r.w4[3] = pk2bf(v1[2], v1[3]);
    return r.s;
  }
}

template <bool PACKED>
__global__ __launch_bounds__(512, 4) void fused_kernel(
    const float* __restrict__ q, const float* __restrict__ qa,
    const float* __restrict__ expw,
    const float* __restrict__ bg, const float* __restrict__ bk,
    const float* __restrict__ br,
    const float* __restrict__ Wg, const float* __restrict__ Wk,
    const float* __restrict__ Wr,
    const unsigned short* __restrict__ wpk,
    float* __restrict__ out) {
  __shared__ char smem[2 * QT_BYTES];              // 50688 B -> 2 blocks/CU
  __shared__ float hlink[64];                      // h at t=64 per local d-col
  const int g = blockIdx.x;
  const int dquad = (g >> 3) & 3;                  // 4 same-b blocks 8 apart: same XCD
  const int b = (g & 7) | ((g >> 5) << 3);         // bijective over 16384
  const int tid = threadIdx.x;
  const int w = tid >> 6;                          // wave 0..7
  const int l = tid & 63;
  const int lrow = l & 15;
  const int lgrp = l >> 4;
  const int mhalf = w >> 2;                        // 0: mt 0-3, 1: mt 4-6
  const int ntq = w & 3;
  const int ntg = dquad * 4 + ntq;                 // global n-tile 0..15
  const int mt0 = mhalf * 4;
  const int Mloc = 4 - mhalf;                      // 4 or 3 m-tiles

  const float* xqa = qa + (size_t)b * 25600;       // x[:, 0:256)
  const float* xq  = q  + (size_t)b * 25600;       // x[:, 256:512)

  // Stage quarter qq (k in [qq*128,+128)) as bf16 into buffer bufi.
  // 3168 f32x4 chunks (99 rows x 32); coalesced; transient regs only.
  // LDS byte-in-row = (c*8) ^ ((row&15)<<4): full 16-column XOR swizzle.
#define STAGE(qq, bufi)                                                      \
  {                                                                          \
    const float* srcb = ((qq) < 2 ? xqa : xq) + ((qq) & 1) * 128;            \
    char* dst = smem + (bufi) * QT_BYTES;                                    \
    _Pragma("unroll")                                                        \
    for (int it = 0; it < 7; ++it) {                                         \
      int cid = it * 512 + tid;                                              \
      if (cid < 3168) {                                                      \
        int row = cid >> 5, c = cid & 31;                                    \
        f32x4 v = *(const f32x4*)(srcb + row * 256 + c * 4);                 \
        unsigned long long pkd =                                             \
            ((unsigned long long)pk2bf(v[2], v[3]) << 32) | pk2bf(v[0], v[1]); \
        int byte = row * 256 + ((c * 8) ^ ((row & 15) << 4));                \
        *(unsigned long long*)(dst + byte) = pkd;                            \
      }                                                                      \
    }                                                                        \
  }

  STAGE(0, 0);
  __syncthreads();

  f32x4 accG[4], accK[4], accR[4];                 // 48 f32/thread (mhalf1: 36)
#pragma unroll
  for (int i = 0; i < 4; ++i) {
    accG[i] = (f32x4){0.f, 0.f, 0.f, 0.f};
    accK[i] = (f32x4){0.f, 0.f, 0.f, 0.f};
    accR[i] = (f32x4){0.f, 0.f, 0.f, 0.f};
  }

  // hoisted fragment addresses: addr = pre[i] ^ (kk*64)
  int pre[4];
#pragma unroll
  for (int i = 0; i < 4; ++i) {
    int t = (mt0 + i) * 16 + lrow;
    t = (t > 98) ? 98 : t;                         // clamped lanes read row 98
    pre[i] = t * 256 + ((lgrp * 16) ^ ((t & 15) << 4));
  }

#pragma unroll
  for (int qq = 0; qq < 4; ++qq) {
    if (qq < 3) STAGE(qq + 1, (qq + 1) & 1);       // other buffer; overlaps GEMM
    const char* base = smem + (qq & 1) * QT_BYTES;
#pragma unroll
    for (int kk = 0; kk < 4; ++kk) {
      const int ks = qq * 4 + kk;
      short8 bG = ldB<PACKED>(wpk, Wg, ntg, ks, l);
      short8 bK = ldB<PACKED>(wpk, Wk, 16 + ntg, ks, l);
      short8 bR = ldB<PACKED>(wpk, Wr, 32 + ntg, ks, l);
#pragma unroll
      for (int i = 0; i < 4; ++i) {
        if (i < Mloc) {                            // wave-uniform predicate
          BF8 a;
          a.s = *(const short8*)(base + (pre[i] ^ (kk * 64)));  // 1 ds_read_b128
          accG[i] = __builtin_amdgcn_mfma_f32_16x16x32_bf16(a.s, bG, accG[i], 0, 0, 0);
          accK[i] = __builtin_amdgcn_mfma_f32_16x16x32_bf16(a.s, bK, accK[i], 0, 0, 0);
          accR[i] = __builtin_amdgcn_mfma_f32_16x16x32_bf16(a.s, bR, accR[i], 0, 0, 0);
        }
      }
    }
    if (qq < 3) __syncthreads();                   // staged visible; buf reads done
  }

  // -------- epilogue: activations + in-register affine scan ----------------
  // acc[i] holds t = (mt0+i)*16 + lgrp*4 + r, d = ntg*16 + lrow.
  // Step: h' = rr*h + cc, cc = (1-rr)*gate*kq. Lane composes its 4 steps into
  // (A,Bc); 4-group shuffle scan; sequential carry across local m-tiles.
  const int d = ntg * 16 + lrow;
  const float bgv = bg[d], bkv = bk[d], brv = br[d];
  float* ob = out + (size_t)b * 25600;
  float h = 0.f;

#define SCAN_MT(I, MTG)                                                      \
  {                                                                          \
    float rr[4], cc[4];                                                      \
    _Pragma("unroll")                                                        \
    for (int r = 0; r < 4; ++r) {                                            \
      const int t = (MTG) * 16 + lgrp * 4 + r;                               \
      if (t < 99) {                                                          \
        float rv = sigm(accR[I][r] + brv);                                   \
        float gv = sigm(accG[I][r] + bgv);                                   \
        float kv = tanh_(accK[I][r] + bkv);                                  \
        rr[r] = rv;                                                          \
        cc[r] = (1.f - rv) * (gv * kv);                                      \
      } else { rr[r] = 1.f; cc[r] = 0.f; }                                   \
    }                                                                        \
    const float A  = ((rr[0] * rr[1]) * rr[2]) * rr[3];                      \
    const float Bc = ((cc[0] * rr[1] + cc[1]) * rr[2] + cc[2]) * rr[3] + cc[3]; \
    float hcur = h, hstart = h;                                              \
    _Pragma("unroll")                                                        \
    for (int gg = 0; gg < 4; ++gg) {                                         \
      float ag  = __shfl(A,  lrow + (gg << 4), 64);                          \
      float bg_ = __shfl(Bc, lrow + (gg << 4), 64);                          \
      hstart = (lgrp == gg) ? hcur : hstart;                                 \
      hcur = __builtin_fmaf(ag, hcur, bg_);                                  \
    }                                                                        \
    h = hcur;                                                                \
    float hh = hstart;                                                       \
    _Pragma("unroll")                                                        \
    for (int r = 0; r < 4; ++r) {                                            \
      const int t = (MTG) * 16 + lgrp * 4 + r;                               \
      hh = __builtin_fmaf(rr[r], hh, cc[r]);                                 \
      if (t < 99) ob[(t + 1) * 256 + d] = hh;                                \
    }                                                                        \
  }

  if (mhalf == 0) {
    h = expw[d];
    if (lgrp == 0) ob[d] = h;                      // out[b,0,:] = exp
    SCAN_MT(0, 0) SCAN_MT(1, 1) SCAN_MT(2, 2) SCAN_MT(3, 3)
    if (lgrp == 0) hlink[ntq * 16 + lrow] = h;     // h at t=64
  }
  __syncthreads();
  if (mhalf == 1) {
    h = hlink[ntq * 16 + lrow];
    SCAN_MT(0, 4) SCAN_MT(1, 5) SCAN_MT(2, 6)
  }
#undef SCAN_MT
#undef STAGE
}

extern "C" void kernel_launch(void* const* d_in, const int* in_sizes, int n_in,
                              void* d_out, int out_size, void* d_ws, size_t ws_size,
                              hipStream_t stream) {
  const float* q    = (const float*)d_in[0];
  const float* qa   = (const float*)d_in[1];
  const float* expw = (const float*)d_in[2];
  const float* Wg   = (const float*)d_in[3];
  const float* bg   = (const float*)d_in[4];
  const float* Wk   = (const float*)d_in[5];
  const float* bk   = (const float*)d_in[6];
  const float* Wr   = (const float*)d_in[7];
  const float* br   = (const float*)d_in[8];
  float* out = (float*)d_out;

  if (ws_size >= W_BYTES) {
    unsigned short* wpk = (unsigned short*)d_ws;
    pack_w<<<192, 256, 0, stream>>>(Wg, Wk, Wr, wpk);
    fused_kernel<true><<<16384, 512, 0, stream>>>(
        q, qa, expw, bg, bk, br, Wg, Wk, Wr, wpk, out);
  } else {
    fused_kernel<false><<<16384, 512, 0, stream>>>(
        q, qa, expw, bg, bk, br, Wg, Wk, Wr, nullptr, out);
  }
}

// Round 10
// 839.152 us; speedup vs baseline: 2.0743x; 1.5370x over previous
//
#include <hip/hip_runtime.h>
#include <hip/hip_bf16.h>

// B=4096, L=100 (SEQLEN=99), d=256, K=2d=512.
// x[b,t,:] = [qa[b,t,:], q[b,t,:]]  (t=0..98)
// gate=sigmoid(x@Wg^T+bg), kq=tanh(x@Wk^T+bk), reset=sigmoid(x@Wr^T+br)
// h_0 = exp; h_{t+1} = r_t*h_t + (1-r_t)*(gate_t*kq_t); out[b] = [exp, h_1..h_99]
//
// Round-10: 256-THREAD blocks break the R2..R9 dichotomy
//   (512-thread blocks: 256 regs @ 1 block/CU [serialized] XOR
//                       128 regs @ 2 blocks/CU [always spilled]).
// 4-wave blocks + __launch_bounds__(256,2): full 256-reg budget AND 2
// independent blocks/CU -> one block's staging/barrier drain hides under the
// partner's MFMA. 84 accs + ~110 arch fits with room; no spill possible.
// Structure: grid 16384 = 4 blocks per b (dquad = 64 d-cols); wave owns one
// 16-col n-tile x all 7 m-tiles (84 acc f32).
//  - x staged in-kernel as bf16 k-quarters (99x128 bf16 = 25344 B), double
//    buffered (50688 B LDS -> 2 blocks/CU), commit-immediate (transient regs).
//    Same-b blocks are stride-8 in grid -> same XCD -> x L2-hot across the 4.
//  - LDS XOR swizzle (row&15)<<4: measured ZERO bank conflicts in R9.
//  - GEMM inner: 3 global B-loads (L2-resident wpk) + 7x(ds_read_b128 + 3
//    MFMA) per kk. All conversion at staging (cvt_pk), none in the loop.
//  - recurrence: in-register affine scan, wave-local carry over 7 m-tiles.

typedef __attribute__((ext_vector_type(4))) float f32x4;
typedef __attribute__((ext_vector_type(8))) short short8;

union BF8 { short8 s; unsigned short u[8]; unsigned int w4[4]; };

static constexpr int QT_BYTES = 99 * 256;        // one bf16 k-quarter, 25344 B
static constexpr size_t W_BYTES = (size_t)48 * 16 * 64 * 16;   // 786432

__device__ __forceinline__ unsigned short f2bf(float f) {
  unsigned int u = __float_as_uint(f);
  return (unsigned short)((u + 0x7fffu + ((u >> 16) & 1u)) >> 16);   // RNE
}

__device__ __forceinline__ unsigned int pk2bf(float lo, float hi) {
  __hip_bfloat162 h = __float22bfloat162_rn(make_float2(lo, hi));    // v_cvt_pk_bf16_f32
  union { __hip_bfloat162 h2; unsigned int u; } cv;
  cv.h2 = h;
  return cv.u;
}

__device__ __forceinline__ float sigm(float x) { return 1.f / (1.f + __expf(-x)); }
__device__ __forceinline__ float tanh_(float x) {
  x = fminf(fmaxf(x, -15.f), 15.f);
  float e = __expf(2.f * x);
  return (e - 1.f) / (e + 1.f);
}

// Pack Wg|Wk|Wr (each 256x512 f32, row-major) into bf16 B-fragment order:
// [nt(48)][ks(16)][lane(64)][j(8)]; value = W_sel[nt%16*16 + (l&15)][ks*32+(l>>4)*8+j]
__global__ void pack_w(const float* __restrict__ Wg, const float* __restrict__ Wk,
                       const float* __restrict__ Wr, unsigned short* __restrict__ out) {
  int idx = blockIdx.x * 256 + threadIdx.x;        // 0 .. 49151  (48*16*64)
  int l = idx & 63;
  int rest = idx >> 6;
  int ks = rest & 15;
  int nt = rest >> 4;                              // 0..47
  int sel = nt >> 4;
  const float* W = (sel == 0) ? Wg : ((sel == 1) ? Wk : Wr);
  int n = ((nt & 15) * 16) + (l & 15);             // 0..255
  const float* p = W + (size_t)n * 512 + ks * 32 + ((l >> 4) * 8);
  unsigned short* o = out + (size_t)idx * 8;
#pragma unroll
  for (int j = 0; j < 8; ++j) o[j] = f2bf(p[j]);
}

template <bool PACKED>
__device__ __forceinline__ short8 ldB(const unsigned short* __restrict__ wpk,
                                      const float* __restrict__ W,
                                      int nt_global, int ks, int l) {
  if constexpr (PACKED) {
    return *(const short8*)(wpk + (((size_t)nt_global * 16 + ks) * 64 + l) * 8);
  } else {
    int n = ((nt_global & 15) * 16) + (l & 15);
    const float* p = W + (size_t)n * 512 + ks * 32 + ((l >> 4) * 8);
    f32x4 v0 = *(const f32x4*)p;
    f32x4 v1 = *(const f32x4*)(p + 4);
    BF8 r;
    r.w4[0] = pk2bf(v0[0], v0[1]); r.w4[1] = pk2bf(v0[2], v0[3]);
    r.w4[2] = pk2bf(v1[0], v1[1]); r.w4[3] = pk2bf(v1[2], v1[3]);
    return r.s;
  }
}

template <bool PACKED>
__global__ __launch_bounds__(256, 2) void fused_kernel(
    const float* __restrict__ q, const float* __restrict__ qa,
    const float* __restrict__ expw,
    const float* __restrict__ bg, const float* __restrict__ bk,
    const float* __restrict__ br,
    const float* __restrict__ Wg, const float* __restrict__ Wk,
    const float* __restrict__ Wr,
    const unsigned short* __restrict__ wpk,
    float* __restrict__ out) {
  __shared__ char smem[2 * QT_BYTES];              // 50688 B; 2 blocks/CU
  const int g = blockIdx.x;
  const int dquad = (g >> 3) & 3;                  // 4 same-b blocks 8 apart: same XCD
  const int b = (g & 7) | ((g >> 5) << 3);         // bijective over 16384
  const int tid = threadIdx.x;
  const int w = tid >> 6;                          // wave 0..3
  const int l = tid & 63;
  const int lrow = l & 15;
  const int lgrp = l >> 4;
  const int ntg = dquad * 4 + w;                   // global n-tile 0..15

  const float* xqa = qa + (size_t)b * 25600;       // x[:, 0:256)
  const float* xq  = q  + (size_t)b * 25600;       // x[:, 256:512)

  // Stage quarter qq (k in [qq*128,+128)) as bf16 into buffer bufi.
  // 3168 f32x4 chunks (99 rows x 32); coalesced; transient regs only.
  // LDS byte-in-row = (c*8) ^ ((row&15)<<4)  -- measured 0 bank conflicts.
#define STAGE(qq, bufi)                                                      \
  {                                                                          \
    const float* srcb = ((qq) < 2 ? xqa : xq) + ((qq) & 1) * 128;            \
    char* dst = smem + (bufi) * QT_BYTES;                                    \
    _Pragma("unroll")                                                        \
    for (int it = 0; it < 13; ++it) {                                        \
      int cid = it * 256 + tid;                                              \
      if (cid < 3168) {                                                      \
        int row = cid >> 5, c = cid & 31;                                    \
        f32x4 v = *(const f32x4*)(srcb + row * 256 + c * 4);                 \
        unsigned long long pkd =                                             \
            ((unsigned long long)pk2bf(v[2], v[3]) << 32) | pk2bf(v[0], v[1]); \
        int byte = row * 256 + ((c * 8) ^ ((row & 15) << 4));                \
        *(unsigned long long*)(dst + byte) = pkd;                            \
      }                                                                      \
    }                                                                        \
  }

  STAGE(0, 0);
  __syncthreads();

  f32x4 accG[7], accK[7], accR[7];                 // 84 f32/thread
#pragma unroll
  for (int mt = 0; mt < 7; ++mt) {
    accG[mt] = (f32x4){0.f, 0.f, 0.f, 0.f};
    accK[mt] = (f32x4){0.f, 0.f, 0.f, 0.f};
    accR[mt] = (f32x4){0.f, 0.f, 0.f, 0.f};
  }

  // hoisted fragment addresses: addr = pre[mt] ^ (kk*64)
  int pre[7];
#pragma unroll
  for (int mt = 0; mt < 7; ++mt) {
    int t = mt * 16 + lrow;
    t = (t > 98) ? 98 : t;                         // clamped lanes read row 98
    pre[mt] = t * 256 + ((lgrp * 16) ^ ((t & 15) << 4));
  }

#pragma unroll
  for (int qq = 0; qq < 4; ++qq) {
    if (qq < 3) STAGE(qq + 1, (qq + 1) & 1);       // other buffer; overlaps GEMM
    const char* base = smem + (qq & 1) * QT_BYTES;
#pragma unroll
    for (int kk = 0; kk < 4; ++kk) {
      const int ks = qq * 4 + kk;
      short8 bG = ldB<PACKED>(wpk, Wg, ntg, ks, l);
      short8 bK = ldB<PACKED>(wpk, Wk, 16 + ntg, ks, l);
      short8 bR = ldB<PACKED>(wpk, Wr, 32 + ntg, ks, l);
#pragma unroll
      for (int mt = 0; mt < 7; ++mt) {
        BF8 a;
        a.s = *(const short8*)(base + (pre[mt] ^ (kk * 64)));   // 1 ds_read_b128
        accG[mt] = __builtin_amdgcn_mfma_f32_16x16x32_bf16(a.s, bG, accG[mt], 0, 0, 0);
        accK[mt] = __builtin_amdgcn_mfma_f32_16x16x32_bf16(a.s, bK, accK[mt], 0, 0, 0);
        accR[mt] = __builtin_amdgcn_mfma_f32_16x16x32_bf16(a.s, bR, accR[mt], 0, 0, 0);
      }
    }
    if (qq < 3) __syncthreads();                   // staged visible; buf reads done
  }

  // -------- epilogue: activations + in-register affine scan ----------------
  // acc[mt] holds t = mt*16 + lgrp*4 + r, d = ntg*16 + lrow.
  // Step: h' = rr*h + cc, cc = (1-rr)*gate*kq. Lane composes its 4 steps into
  // (A,Bc); 4-group shuffle scan; sequential carry across the 7 m-tiles.
  const int d = ntg * 16 + lrow;
  const float bgv = bg[d], bkv = bk[d], brv = br[d];
  float* ob = out + (size_t)b * 25600;
  float h = expw[d];
  if (lgrp == 0) ob[d] = h;                        // out[b,0,:] = exp
#pragma unroll
  for (int mt = 0; mt < 7; ++mt) {
    float rr[4], cc[4];
#pragma unroll
    for (int r = 0; r < 4; ++r) {
      const int t = mt * 16 + lgrp * 4 + r;
      if (t < 99) {
        float rv = sigm(accR[mt][r] + brv);
        float gv = sigm(accG[mt][r] + bgv);
        float kv = tanh_(accK[mt][r] + bkv);
        rr[r] = rv;
        cc[r] = (1.f - rv) * (gv * kv);
      } else { rr[r] = 1.f; cc[r] = 0.f; }         // identity step for padding
    }
    // compose this lane's 4 steps: h -> A*h + B
    const float A  = ((rr[0] * rr[1]) * rr[2]) * rr[3];
    const float Bc = ((cc[0] * rr[1] + cc[1]) * rr[2] + cc[2]) * rr[3] + cc[3];
    // shuffle scan across the 4 lgrp groups (same lrow column)
    float hcur = h, hstart = h;
#pragma unroll
    for (int gg = 0; gg < 4; ++gg) {
      float ag  = __shfl(A,  lrow + (gg << 4), 64);
      float bg_ = __shfl(Bc, lrow + (gg << 4), 64);
      hstart = (lgrp == gg) ? hcur : hstart;       // exclusive prefix for own group
      hcur = __builtin_fmaf(ag, hcur, bg_);
    }
    h = hcur;                                      // carry to next m-tile
    // reconstruct the 4 per-step h values and store
    float hh = hstart;
#pragma unroll
    for (int r = 0; r < 4; ++r) {
      const int t = mt * 16 + lgrp * 4 + r;
      hh = __builtin_fmaf(rr[r], hh, cc[r]);
      if (t < 99) ob[(t + 1) * 256 + d] = hh;
    }
  }
#undef STAGE
}

extern "C" void kernel_launch(void* const* d_in, const int* in_sizes, int n_in,
                              void* d_out, int out_size, void* d_ws, size_t ws_size,
                              hipStream_t stream) {
  const float* q    = (const float*)d_in[0];
  const float* qa   = (const float*)d_in[1];
  const float* expw = (const float*)d_in[2];
  const float* Wg   = (const float*)d_in[3];
  const float* bg   = (const float*)d_in[4];
  const float* Wk   = (const float*)d_in[5];
  const float* bk   = (const float*)d_in[6];
  const float* Wr   = (const float*)d_in[7];
  const float* br   = (const float*)d_in[8];
  float* out = (float*)d_out;

  if (ws_size >= W_BYTES) {
    unsigned short* wpk = (unsigned short*)d_ws;
    pack_w<<<192, 256, 0, stream>>>(Wg, Wk, Wr, wpk);
    fused_kernel<true><<<16384, 256, 0, stream>>>(
        q, qa, expw, bg, bk, br, Wg, Wk, Wr, wpk, out);
  } else {
    fused_kernel<false><<<16384, 256, 0, stream>>>(
        q, qa, expw, bg, bk, br, Wg, Wk, Wr, nullptr, out);
  }
}